// Round 4
// baseline (164.084 us; speedup 1.0000x reference)
//
#include <hip/hip_runtime.h>

// ---------------------------------------------------------------------------
// color_invariant_quadruplet: 3-hop label gather + 6-way equality embedding sum
//
// The 6 equality bits take 64 combinations; each maps to a fixed 64-float row.
// Pipeline (3 one-shot kernels):
//   K1 : hop1 packed labels (4 edges/thread) + table build (blocks 0..15)
//   K2 : hop2 packed (z_ss, z_dd)            (4 edges/thread)
//   KW : fused combo+write: 256 edges/block; phase1 computes combo bytes into
//        LDS (2 random gathers/thread), phase2 emits 16 independent coalesced
//        1KB wave-stores per wave from an LDS-staged table.
//
// Round 4 change: fuse K3a+K3b (kill the 2MB combo round-trip + one dispatch,
// overlap gather latency of block N+1 with store BW of block N), fold K0 into
// K1. NO grid-stride dependent chains (round-2 lesson).
// ---------------------------------------------------------------------------

#define N_FEAT 64

__device__ __forceinline__ unsigned combo6(unsigned p, unsigned q) {
    // p = (za | zc<<8), q = (zb | zd<<8)
    unsigned za = p & 0xffu, zc = p >> 8;
    unsigned zb = q & 0xffu, zd = q >> 8;
    return (unsigned)(za == zc)
         | ((unsigned)(za == zb) << 1)
         | ((unsigned)(zc == zb) << 2)
         | ((unsigned)(za == zd) << 3)
         | ((unsigned)(zc == zd) << 4)
         | ((unsigned)(zb == zd) << 5);
}

// K1: hop1, 4 g-edges/thread (8 independent random z-gathers in flight).
// zg[e] = z_src | z_dst<<8 (z in 0..7 fits a byte).
// Blocks 0..15 additionally build the 64x64 table with the reference
// left-to-right f32 add order (bit-exact). Table is consumed 2 dispatches
// later (KW), so this hides the former K0 dispatch entirely.
__global__ void hop1_table_kernel(const int* __restrict__ z,
                                  const int* __restrict__ src_g,
                                  const int* __restrict__ dst_g,
                                  unsigned short* __restrict__ zg,
                                  const float* __restrict__ e1,
                                  const float* __restrict__ e2,
                                  const float* __restrict__ e3,
                                  const float* __restrict__ e4,
                                  const float* __restrict__ e5,
                                  const float* __restrict__ e6,
                                  float* __restrict__ table,
                                  int n) {
    int i  = blockIdx.x * blockDim.x + threadIdx.x;
    int n4 = n >> 2;
    if (i < n4) {
        int4 s = ((const int4*)src_g)[i];
        int4 d = ((const int4*)dst_g)[i];
        unsigned zs0 = (unsigned)z[s.x], zd0 = (unsigned)z[d.x];
        unsigned zs1 = (unsigned)z[s.y], zd1 = (unsigned)z[d.y];
        unsigned zs2 = (unsigned)z[s.z], zd2 = (unsigned)z[d.z];
        unsigned zs3 = (unsigned)z[s.w], zd3 = (unsigned)z[d.w];
        unsigned r0 = (zs0 & 0xffu) | ((zd0 & 0xffu) << 8)
                    | ((zs1 & 0xffu) << 16) | ((zd1 & 0xffu) << 24);
        unsigned r1 = (zs2 & 0xffu) | ((zd2 & 0xffu) << 8)
                    | ((zs3 & 0xffu) << 16) | ((zd3 & 0xffu) << 24);
        ((uint2*)zg)[i] = make_uint2(r0, r1);
    } else {
        int e = (n4 << 2) + (i - n4);      // tail edges, scalar
        if (e < n) {
            zg[e] = (unsigned short)(((unsigned)z[src_g[e]] & 0xffu)
                                   | (((unsigned)z[dst_g[e]] & 0xffu) << 8));
        }
    }
    if (blockIdx.x < 16) {
        int idx = blockIdx.x * 256 + threadIdx.x;   // 0..4095
        int cmb = idx >> 6;
        int f   = idx & (N_FEAT - 1);
        float v = e1[((cmb >> 0) & 1) * N_FEAT + f];
        v      += e2[((cmb >> 1) & 1) * N_FEAT + f];
        v      += e3[((cmb >> 2) & 1) * N_FEAT + f];
        v      += e4[((cmb >> 3) & 1) * N_FEAT + f];
        v      += e5[((cmb >> 4) & 1) * N_FEAT + f];
        v      += e6[((cmb >> 5) & 1) * N_FEAT + f];
        table[idx] = v;
    }
}

// K2: hop2, 4 h-edges/thread. zh = z_src[src_h] | z_dst[dst_h]<<8.
__global__ void hop2_kernel(const unsigned short* __restrict__ zg,
                            const int* __restrict__ src_h,
                            const int* __restrict__ dst_h,
                            unsigned short* __restrict__ zh,
                            int n) {
    int i  = blockIdx.x * blockDim.x + threadIdx.x;
    int n4 = n >> 2;
    if (i < n4) {
        int4 s = ((const int4*)src_h)[i];
        int4 d = ((const int4*)dst_h)[i];
        unsigned a0 = zg[s.x], b0 = zg[d.x];
        unsigned a1 = zg[s.y], b1 = zg[d.y];
        unsigned a2 = zg[s.z], b2 = zg[d.z];
        unsigned a3 = zg[s.w], b3 = zg[d.w];
        unsigned r0 = (a0 & 0xffu) | (b0 & 0xff00u)
                    | ((a1 & 0xffu) << 16) | ((b1 & 0xff00u) << 16);
        unsigned r1 = (a2 & 0xffu) | (b2 & 0xff00u)
                    | ((a3 & 0xffu) << 16) | ((b3 & 0xff00u) << 16);
        ((uint2*)zh)[i] = make_uint2(r0, r1);
    } else {
        int e = (n4 << 2) + (i - n4);
        if (e < n) {
            unsigned a = zg[src_h[e]], b = zg[dst_h[e]];
            zh[e] = (unsigned short)((a & 0xffu) | (b & 0xff00u));
        }
    }
}

// KW: fused combo + streaming write. 256 edges (64 KB output) per block.
// Phase 1: thread t computes combo byte for edge block*256+t -> LDS.
//          (coalesced src_i/dst_i dword loads, 2 independent random zh
//           gathers; table staged to LDS in parallel, 16.25 KB LDS total)
// Phase 2: 16 independent coalesced stores/thread; store k of a wave covers
//          a contiguous 1 KB range. Data comes from LDS only (no global
//          loads in the store chain). Gather latency of co-resident blocks'
//          phase 1 overlaps store BW of phase 2.
__global__ __launch_bounds__(256)
void fused_write_kernel(const unsigned short* __restrict__ zh,
                        const int* __restrict__ src_i,
                        const int* __restrict__ dst_i,
                        const float* __restrict__ table,
                        float* __restrict__ out,
                        int nEdges) {
    __shared__ float4 tbl[64 * 16];            // 16 KB: 64 rows x 16 float4
    __shared__ unsigned char cmb[256];         // this block's combo bytes
    const int tid = threadIdx.x;

    // phase 1a: this thread's edge -> combo byte (issue idx loads first)
    const long long e0 = (long long)blockIdx.x * 256;
    const int e = (int)e0 + tid;
    if (e < nEdges) {
        unsigned p = zh[src_i[e]];     // za | zc<<8
        unsigned q = zh[dst_i[e]];     // zb | zd<<8
        cmb[tid] = (unsigned char)combo6(p, q);
    }
    // phase 1b: stage table (independent of combo path)
    const float4* t4 = (const float4*)table;
#pragma unroll
    for (int k = 0; k < 4; ++k)
        tbl[k * 256 + tid] = t4[k * 256 + tid];
    __syncthreads();

    // phase 2: 4096 float4s per block; thread t writes f4 (k*256 + t).
    // f & 15 == tid & 15 (block base is a multiple of 4096).
    const long long base  = e0 * 16;
    const long long total = (long long)nEdges * 16;
    const int c = tid & 15;
#pragma unroll
    for (int k = 0; k < 16; ++k) {
        long long f = base + k * 256 + tid;
        if (f < total) {
            int le = k * 16 + (tid >> 4);          // local edge 0..255
            ((float4*)out)[f] = tbl[cmb[le] * 16 + c];
        }
    }
}

extern "C" void kernel_launch(void* const* d_in, const int* in_sizes, int n_in,
                              void* d_out, int out_size, void* d_ws, size_t ws_size,
                              hipStream_t stream) {
    // setup_inputs order: z, src_g, dst_g, src_h, dst_h, src_i, dst_i, e1..e6
    const int* z     = (const int*)d_in[0];
    const int* src_g = (const int*)d_in[1];
    const int* dst_g = (const int*)d_in[2];
    const int* src_h = (const int*)d_in[3];
    const int* dst_h = (const int*)d_in[4];
    const int* src_i = (const int*)d_in[5];
    const int* dst_i = (const int*)d_in[6];
    const float* e1  = (const float*)d_in[7];
    const float* e2  = (const float*)d_in[8];
    const float* e3  = (const float*)d_in[9];
    const float* e4  = (const float*)d_in[10];
    const float* e5  = (const float*)d_in[11];
    const float* e6  = (const float*)d_in[12];

    int E_G = in_sizes[1];
    int E_H = in_sizes[3];
    int E_I = in_sizes[5];

    // Workspace layout (256B-aligned):
    //   [0, 16384)   : float table[64][64]
    //   [+2*E_G]     : ushort zg[E_G]
    //   [+2*E_H]     : ushort zh[E_H]
    char* ws = (char*)d_ws;
    float* table = (float*)ws;
    size_t off   = 64 * N_FEAT * sizeof(float);               // 16384
    unsigned short* zg = (unsigned short*)(ws + off);
    off += (size_t)E_G * sizeof(unsigned short);
    off  = (off + 255) & ~(size_t)255;
    unsigned short* zh = (unsigned short*)(ws + off);

    float* out = (float*)d_out;

    // K1: hop1 + table build (>=16 blocks always: E_G/4/256 = 977 here)
    {
        int n4 = E_G >> 2, nth = n4 + (E_G - (n4 << 2));
        int blocks = (nth + 255) / 256;
        if (blocks < 16) blocks = 16;
        hop1_table_kernel<<<blocks, 256, 0, stream>>>(z, src_g, dst_g, zg,
                                                      e1, e2, e3, e4, e5, e6,
                                                      table, E_G);
    }
    // K2
    {
        int n4 = E_H >> 2, nth = n4 + (E_H - (n4 << 2));
        hop2_kernel<<<(nth + 255) / 256, 256, 0, stream>>>(zg, src_h, dst_h, zh, E_H);
    }
    // KW: 256 edges per block
    {
        int blocks = (E_I + 255) / 256;
        fused_write_kernel<<<blocks, 256, 0, stream>>>(zh, src_i, dst_i, table, out, E_I);
    }
}